// Round 1
// baseline (654.251 us; speedup 1.0000x reference)
//
#include <hip/hip_runtime.h>
#include <hip/hip_bf16.h>
#include <stdint.h>

// Problem constants
#define T_DIM 2048
#define B_DIM 8
#define D_DIM 1024
#define NSTATE 1024
#define BLKSZ 8
#define NB 128
#define M_DIM (T_DIM * B_DIM)   // 16384
#define N_DIM (3 * NSTATE)      // 3072 (k | v | q concatenated)
#define K_DIM D_DIM             // 1024

typedef __bf16 bf16x8 __attribute__((ext_vector_type(8)));
typedef float f32x4 __attribute__((ext_vector_type(4)));
typedef unsigned int uintx4 __attribute__((ext_vector_type(4)));

typedef __attribute__((address_space(3))) void lds_void;
typedef __attribute__((address_space(1))) const void glb_void;

__device__ __forceinline__ unsigned short f2bf(float f) {
  unsigned u = __float_as_uint(f);
  u = (u + 0x7FFFu + ((u >> 16) & 1u)) >> 16;  // RNE
  return (unsigned short)u;
}
__device__ __forceinline__ float bf2f(unsigned short h) {
  return __uint_as_float(((unsigned)h) << 16);
}
// unpack bf16 #hi (0=low,1=high) from a packed u32, as float (1 VALU op)
__device__ __forceinline__ float bfu(unsigned r, int hi) {
  return __uint_as_float(hi ? (r & 0xFFFF0000u) : (r << 16));
}

__device__ __forceinline__ void load_lds16(const unsigned short* g,
                                           unsigned short* l) {
  __builtin_amdgcn_global_load_lds((glb_void*)g, (lds_void*)l, 16, 0, 0);
}

// 8-lane butterfly sum-broadcast via DPP (groups = physical lanes 8k..8k+7)
template <int CTRL>
__device__ __forceinline__ float dpp_add(float x) {
  int y = __builtin_amdgcn_update_dpp(0, __float_as_int(x), CTRL, 0xF, 0xF, true);
  return x + __int_as_float(y);
}
__device__ __forceinline__ float reduce8(float x) {
  x = dpp_add<0xB1>(x);   // quad_perm(1,0,3,2): lane ^ 1
  x = dpp_add<0x4E>(x);   // quad_perm(2,3,0,1): lane ^ 2
  x = dpp_add<0x141>(x);  // row_half_mirror: crosses quads within 8-group
  return x;
}

// ---------------- Kernel 1: fp32 -> bf16 conversion of x and Wcat ----------
__global__ __launch_bounds__(256) void convert_kernel(
    const float* __restrict__ x, const float* __restrict__ Wk,
    const float* __restrict__ Wv, const float* __restrict__ Wq,
    unsigned short* __restrict__ xb, unsigned short* __restrict__ wb) {
  size_t idx = (size_t)blockIdx.x * blockDim.x + threadIdx.x;
  size_t row = idx >> 8;
  int c4 = (int)(idx & 255) * 4;
  const float* src;
  unsigned short* dst;
  if (row < (size_t)M_DIM) {
    src = x + row * K_DIM;
    dst = xb + row * K_DIM;
  } else {
    size_t r = row - M_DIM;
    const float* w = (r < 1024) ? Wk : (r < 2048 ? Wv : Wq);
    src = w + (r & 1023) * K_DIM;
    dst = wb + r * K_DIM;
  }
  float4 v = *(const float4*)(src + c4);
  ushort4 o;
  o.x = f2bf(v.x); o.y = f2bf(v.y); o.z = f2bf(v.z); o.w = f2bf(v.w);
  *(ushort4*)(dst + c4) = o;
}

// ---------------- Kernel 2: bf16 MFMA GEMM, chain-major packed epilogue ----
// NEW pk layout (vector-load friendly for the scan):
//   pk[chain][tblk=t/8][seg(k,v,q)][elem 0..7][t%8]   (ushorts)
//   per chain plane = 2048*24 = 49152 ushorts; per tblk = 192 ushorts.
// Scan lane (i,j) then reads its 8-step stream of k[j] / v[i] / q[j] as one
// dwordx4 each. k is normalized IN the epilogue (fp32, DPP reduce over the
// 8 j-lanes) as before.
#define BM 128
#define BN 128
#define BK 32
#define C_PLANE 49152  // ushorts per chain

__global__ __launch_bounds__(256) void gemm_kernel(
    const unsigned short* __restrict__ A,     // [M][K] bf16
    const unsigned short* __restrict__ Bmat,  // [N][K] bf16
    unsigned short* __restrict__ pk) {        // packed, layout above
  __shared__ unsigned short As[BM * BK];  // swizzled, unpadded
  __shared__ unsigned short Bs[BN * BK];

  const int tid = threadIdx.x;
  const int nTiles = N_DIM / BN;  // 24
  const int nTile = blockIdx.x % nTiles;
  const int mTile = blockIdx.x / nTiles;
  const int m0 = mTile * BM, n0 = nTile * BN;

  const int lane = tid & 63, wave = tid >> 6;
  const int wm = wave >> 1, wn = wave & 1;
  const int l15 = lane & 15, quad = lane >> 4;
  const int sw = quad ^ ((l15 >> 1) & 3);

  const int srow = lane >> 2;
  const int sblk = (lane & 3) ^ ((lane >> 3) & 3);
  const int c0 = wave, c1 = wave + 4;

  const unsigned short* gA0 = A + (size_t)(m0 + c0 * 16 + srow) * K_DIM + sblk * 8;
  const unsigned short* gA1 = A + (size_t)(m0 + c1 * 16 + srow) * K_DIM + sblk * 8;
  const unsigned short* gB0 = Bmat + (size_t)(n0 + c0 * 16 + srow) * K_DIM + sblk * 8;
  const unsigned short* gB1 = Bmat + (size_t)(n0 + c1 * 16 + srow) * K_DIM + sblk * 8;

  f32x4 acc[4][4];
#pragma unroll
  for (int mi = 0; mi < 4; mi++)
#pragma unroll
    for (int ni = 0; ni < 4; ni++) acc[mi][ni] = (f32x4){0.f, 0.f, 0.f, 0.f};

  for (int k0 = 0; k0 < K_DIM; k0 += BK) {
    __syncthreads();
    load_lds16(gA0 + k0, As + c0 * 512);
    load_lds16(gA1 + k0, As + c1 * 512);
    load_lds16(gB0 + k0, Bs + c0 * 512);
    load_lds16(gB1 + k0, Bs + c1 * 512);
    __syncthreads();

    bf16x8 af[4], bfr[4];
#pragma unroll
    for (int mi = 0; mi < 4; mi++) {
      uintx4 r = *(const uintx4*)(As + (wm * 64 + mi * 16 + l15) * BK + sw * 8);
      af[mi] = __builtin_bit_cast(bf16x8, r);
    }
#pragma unroll
    for (int ni = 0; ni < 4; ni++) {
      uintx4 r = *(const uintx4*)(Bs + (wn * 64 + ni * 16 + l15) * BK + sw * 8);
      bfr[ni] = __builtin_bit_cast(bf16x8, r);
    }
#pragma unroll
    for (int mi = 0; mi < 4; mi++)
#pragma unroll
      for (int ni = 0; ni < 4; ni++)
        acc[mi][ni] = __builtin_amdgcn_mfma_f32_16x16x32_bf16(
            af[mi], bfr[ni], acc[mi][ni], 0, 0, 0);
  }

  // Epilogue: scatter into [chain][tblk][seg][elem][t%8]; normalize k rows.
#pragma unroll
  for (int mi = 0; mi < 4; mi++) {
#pragma unroll
    for (int ni = 0; ni < 4; ni++) {
      const int col = n0 + wn * 64 + ni * 16 + l15;
      const int seg = col >> 10;        // 0=k 1=v 2=q (uniform per block)
      const int wcol = col & 1023;
      const int nbq = wcol >> 3, jq = wcol & 7;
#pragma unroll
      for (int r = 0; r < 4; r++) {
        const int rowg = m0 + wm * 64 + mi * 16 + quad * 4 + r;
        const int t = rowg >> 3, bq = rowg & 7;
        float val = acc[mi][ni][r];
        if (seg == 0) {  // wave-uniform branch
          float ss = reduce8(val * val);  // ||k||^2 over the 8 j-lanes
          float rs = __builtin_amdgcn_rcpf(__builtin_amdgcn_sqrtf(ss) + 1e-6f);
          val *= rs;
        }
        const size_t addr = (size_t)(bq * NB + nbq) * C_PLANE +
                            (size_t)(t >> 3) * 192 + seg * 64 + jq * 8 +
                            (t & 7);
        pk[addr] = f2bf(val);
      }
    }
  }
}

// ---------------- Kernel 3: scan, TWO chains per wave (ILP latency hiding) -
// 512 blocks x 64 threads. Wave handles chains (2b, 2b+1); lane (i,j) holds
// S0[i][j] and S1[i][j]. The two independent dependency chains are
// interleaved instruction-by-instruction so chain B's ops fill chain A's
// dependency stalls (1 wave/SIMD -> no TLP available; ILP is the only hiding).
// Streams are consumed as dwordx4 (8 steps per load), double-buffered one
// 8-step block ahead.
#define C_2LOG2E 2.8853900817779268f   // 2*log2(e)
#define C_LOG2E  1.4426950408889634f

__device__ __forceinline__ void step2(float& S0, float& S1, float k0, float v0,
                                      float q0, float k1, float v1, float q1,
                                      float& o0, float& o1) {
  // retrieved_i = sum_j S[i][j]*kn[j]  (k pre-normalized)
  float p0 = S0 * k0, p1 = S1 * k1;
  p0 = dpp_add<0xB1>(p0);  p1 = dpp_add<0xB1>(p1);
  p0 = dpp_add<0x4E>(p0);  p1 = dpp_add<0x4E>(p1);
  p0 = dpp_add<0x141>(p0); p1 = dpp_add<0x141>(p1);
  float d0 = v0 - p0, d1 = v1 - p1;
  // S = tanh(S + delta*kn)
  float a0 = fmaf(d0, k0, S0), a1 = fmaf(d1, k1, S1);
  float e0 = __builtin_amdgcn_exp2f(a0 * C_2LOG2E);
  float e1 = __builtin_amdgcn_exp2f(a1 * C_2LOG2E);
  S0 = fmaf(-2.f, __builtin_amdgcn_rcpf(e0 + 1.f), 1.f);
  S1 = fmaf(-2.f, __builtin_amdgcn_rcpf(e1 + 1.f), 1.f);
  // z_i = sum_j S[i][j]*q[j]; out = z^2 * sigmoid(z)
  float z0 = S0 * q0, z1 = S1 * q1;
  z0 = dpp_add<0xB1>(z0);  z1 = dpp_add<0xB1>(z1);
  z0 = dpp_add<0x4E>(z0);  z1 = dpp_add<0x4E>(z1);
  z0 = dpp_add<0x141>(z0); z1 = dpp_add<0x141>(z1);
  float g0 = __builtin_amdgcn_rcpf(1.f + __builtin_amdgcn_exp2f(-z0 * C_LOG2E));
  float g1 = __builtin_amdgcn_rcpf(1.f + __builtin_amdgcn_exp2f(-z1 * C_LOG2E));
  o0 = z0 * z0 * g0;
  o1 = z1 * z1 * g1;
}

__global__ __launch_bounds__(64) void scan_kernel(
    const unsigned short* __restrict__ pk, float* __restrict__ out) {
  const int pair = blockIdx.x;           // 0..511
  const int c0 = pair * 2, c1 = c0 + 1;  // same b (NB=128 even)
  const int lane = threadIdx.x;
  const int i = lane >> 3, j = lane & 7;

  const uintx4* s0 = (const uintx4*)(pk + (size_t)c0 * C_PLANE);
  const uintx4* s1 = (const uintx4*)(pk + (size_t)c1 * C_PLANE);
  const int ko = j, vo = 8 + i, qo = 16 + j;  // chunk index within tblk (24)

  float S0 = 0.f, S1 = 0.f;
  uintx4 ck0 = s0[ko], cv0 = s0[vo], cq0 = s0[qo];
  uintx4 ck1 = s1[ko], cv1 = s1[vo], cq1 = s1[qo];

  const int b = c0 >> 7, nb0 = c0 & 127;
  float* outp = out + (size_t)b * NSTATE + nb0 * BLKSZ + i;
  const bool writer = (j == 0);

  for (int tb = 0; tb < 256; tb++) {
    const int nx = (tb < 255 ? tb + 1 : 255) * 24;  // clamp: harmless re-read
    uintx4 nk0 = s0[nx + ko], nv0 = s0[nx + vo], nq0 = s0[nx + qo];
    uintx4 nk1 = s1[nx + ko], nv1 = s1[nx + vo], nq1 = s1[nx + qo];
#pragma unroll
    for (int u = 0; u < 8; u++) {
      float k0 = bfu(ck0[u >> 1], u & 1);
      float v0f = bfu(cv0[u >> 1], u & 1);
      float q0f = bfu(cq0[u >> 1], u & 1);
      float k1 = bfu(ck1[u >> 1], u & 1);
      float v1f = bfu(cv1[u >> 1], u & 1);
      float q1f = bfu(cq1[u >> 1], u & 1);
      float o0, o1;
      step2(S0, S1, k0, v0f, q0f, k1, v1f, q1f, o0, o1);
      if (writer) {
        const size_t off = (size_t)(tb * 8 + u) * (B_DIM * NSTATE);
        outp[off] = o0;
        outp[off + BLKSZ] = o1;  // chain c1 = c0+1 -> +8 floats
      }
    }
    ck0 = nk0; cv0 = nv0; cq0 = nq0;
    ck1 = nk1; cv1 = nv1; cq1 = nq1;
  }

  // S_final: [B][NB][8][8]; lane (i,j) -> element i*8+j, coalesced
  const size_t fin = (size_t)T_DIM * B_DIM * NSTATE;
  out[fin + (size_t)c0 * 64 + lane] = S0;
  out[fin + (size_t)c1 * 64 + lane] = S1;
}

// ---------------- launch ---------------------------------------------------
extern "C" void kernel_launch(void* const* d_in, const int* in_sizes, int n_in,
                              void* d_out, int out_size, void* d_ws,
                              size_t ws_size, hipStream_t stream) {
  const float* x = (const float*)d_in[0];
  const float* Wk = (const float*)d_in[1];
  const float* Wv = (const float*)d_in[2];
  const float* Wq = (const float*)d_in[3];
  float* out = (float*)d_out;

  unsigned short* xb = (unsigned short*)d_ws;                  // 32 MiB
  unsigned short* wb = xb + (size_t)M_DIM * K_DIM;             // 6 MiB
  unsigned short* pk = wb + (size_t)N_DIM * K_DIM;             // 96 MiB packed

  convert_kernel<<<M_DIM + N_DIM, 256, 0, stream>>>(x, Wk, Wv, Wq, xb, wb);
  gemm_kernel<<<(M_DIM / BM) * (N_DIM / BN), 256, 0, stream>>>(xb, wb, pk);
  scan_kernel<<<B_DIM * NB / 2, 64, 0, stream>>>(pk, out);
}

// Round 2
// 604.604 us; speedup vs baseline: 1.0821x; 1.0821x over previous
//
#include <hip/hip_runtime.h>
#include <hip/hip_bf16.h>
#include <stdint.h>

// Problem constants
#define T_DIM 2048
#define B_DIM 8
#define D_DIM 1024
#define NSTATE 1024
#define BLKSZ 8
#define NB 128
#define M_DIM (T_DIM * B_DIM)   // 16384
#define N_DIM (3 * NSTATE)      // 3072 (k | v | q concatenated)
#define K_DIM D_DIM             // 1024

typedef __bf16 bf16x8 __attribute__((ext_vector_type(8)));
typedef float f32x4 __attribute__((ext_vector_type(4)));
typedef unsigned int uintx4 __attribute__((ext_vector_type(4)));

typedef __attribute__((address_space(3))) void lds_void;
typedef __attribute__((address_space(1))) const void glb_void;

__device__ __forceinline__ unsigned short f2bf(float f) {
  unsigned u = __float_as_uint(f);
  u = (u + 0x7FFFu + ((u >> 16) & 1u)) >> 16;  // RNE
  return (unsigned short)u;
}
// unpack bf16 #hi (0=low,1=high) from a packed u32, as float (1 VALU op)
__device__ __forceinline__ float bfu(unsigned r, int hi) {
  return __uint_as_float(hi ? (r & 0xFFFF0000u) : (r << 16));
}

__device__ __forceinline__ void load_lds16(const unsigned short* g,
                                           unsigned short* l) {
  __builtin_amdgcn_global_load_lds((glb_void*)g, (lds_void*)l, 16, 0, 0);
}

// DPP butterfly add (groups = physical lanes)
template <int CTRL>
__device__ __forceinline__ float dpp_add(float x) {
  int y = __builtin_amdgcn_update_dpp(0, __float_as_int(x), CTRL, 0xF, 0xF, true);
  return x + __int_as_float(y);
}
__device__ __forceinline__ float reduce8(float x) {
  x = dpp_add<0xB1>(x);   // quad_perm(1,0,3,2): lane ^ 1
  x = dpp_add<0x4E>(x);   // quad_perm(2,3,0,1): lane ^ 2
  x = dpp_add<0x141>(x);  // row_half_mirror: crosses quads within 8-group
  return x;
}

// ---------------- Kernel 1: fp32 -> bf16 conversion of x and Wcat ----------
__global__ __launch_bounds__(256) void convert_kernel(
    const float* __restrict__ x, const float* __restrict__ Wk,
    const float* __restrict__ Wv, const float* __restrict__ Wq,
    unsigned short* __restrict__ xb, unsigned short* __restrict__ wb) {
  size_t idx = (size_t)blockIdx.x * blockDim.x + threadIdx.x;
  size_t row = idx >> 8;
  int c4 = (int)(idx & 255) * 4;
  const float* src;
  unsigned short* dst;
  if (row < (size_t)M_DIM) {
    src = x + row * K_DIM;
    dst = xb + row * K_DIM;
  } else {
    size_t r = row - M_DIM;
    const float* w = (r < 1024) ? Wk : (r < 2048 ? Wv : Wq);
    src = w + (r & 1023) * K_DIM;
    dst = wb + r * K_DIM;
  }
  float4 v = *(const float4*)(src + c4);
  ushort4 o;
  o.x = f2bf(v.x); o.y = f2bf(v.y); o.z = f2bf(v.z); o.w = f2bf(v.w);
  *(ushort4*)(dst + c4) = o;
}

// ---------------- Kernel 2: bf16 MFMA GEMM, chain-major packed epilogue ----
// pk layout per chain, per 8-step block (tblk = t/8), 192 ushorts:
//   k: [h][u][e]  -> off       h*32 + u*4 + e   (h=j>>2, e=j&3, u=t%8)
//   v: [i][u]     -> off  64 + i*8  + u
//   q: [h][u][e]  -> off 128 + h*32 + u*4 + e
// Scan lane (c,i,h) then streams k/q as 4x dwordx4 (64B per tblk) and v as
// one dwordx4 (16B per tblk). k is normalized IN the epilogue as before.
#define BM 128
#define BN 128
#define BK 32
#define C_PLANE 49152  // ushorts per chain (256 tblk * 192)

__global__ __launch_bounds__(256) void gemm_kernel(
    const unsigned short* __restrict__ A,     // [M][K] bf16
    const unsigned short* __restrict__ Bmat,  // [N][K] bf16
    unsigned short* __restrict__ pk) {        // packed, layout above
  __shared__ unsigned short As[BM * BK];  // swizzled, unpadded
  __shared__ unsigned short Bs[BN * BK];

  const int tid = threadIdx.x;
  const int nTiles = N_DIM / BN;  // 24
  const int nTile = blockIdx.x % nTiles;
  const int mTile = blockIdx.x / nTiles;
  const int m0 = mTile * BM, n0 = nTile * BN;

  const int lane = tid & 63, wave = tid >> 6;
  const int wm = wave >> 1, wn = wave & 1;
  const int l15 = lane & 15, quad = lane >> 4;
  const int sw = quad ^ ((l15 >> 1) & 3);

  const int srow = lane >> 2;
  const int sblk = (lane & 3) ^ ((lane >> 3) & 3);
  const int c0 = wave, c1 = wave + 4;

  const unsigned short* gA0 = A + (size_t)(m0 + c0 * 16 + srow) * K_DIM + sblk * 8;
  const unsigned short* gA1 = A + (size_t)(m0 + c1 * 16 + srow) * K_DIM + sblk * 8;
  const unsigned short* gB0 = Bmat + (size_t)(n0 + c0 * 16 + srow) * K_DIM + sblk * 8;
  const unsigned short* gB1 = Bmat + (size_t)(n0 + c1 * 16 + srow) * K_DIM + sblk * 8;

  f32x4 acc[4][4];
#pragma unroll
  for (int mi = 0; mi < 4; mi++)
#pragma unroll
    for (int ni = 0; ni < 4; ni++) acc[mi][ni] = (f32x4){0.f, 0.f, 0.f, 0.f};

  for (int k0 = 0; k0 < K_DIM; k0 += BK) {
    __syncthreads();
    load_lds16(gA0 + k0, As + c0 * 512);
    load_lds16(gA1 + k0, As + c1 * 512);
    load_lds16(gB0 + k0, Bs + c0 * 512);
    load_lds16(gB1 + k0, Bs + c1 * 512);
    __syncthreads();

    bf16x8 af[4], bfr[4];
#pragma unroll
    for (int mi = 0; mi < 4; mi++) {
      uintx4 r = *(const uintx4*)(As + (wm * 64 + mi * 16 + l15) * BK + sw * 8);
      af[mi] = __builtin_bit_cast(bf16x8, r);
    }
#pragma unroll
    for (int ni = 0; ni < 4; ni++) {
      uintx4 r = *(const uintx4*)(Bs + (wn * 64 + ni * 16 + l15) * BK + sw * 8);
      bfr[ni] = __builtin_bit_cast(bf16x8, r);
    }
#pragma unroll
    for (int mi = 0; mi < 4; mi++)
#pragma unroll
      for (int ni = 0; ni < 4; ni++)
        acc[mi][ni] = __builtin_amdgcn_mfma_f32_16x16x32_bf16(
            af[mi], bfr[ni], acc[mi][ni], 0, 0, 0);
  }

  // Epilogue: scatter into [chain][tblk][...] records; normalize k rows.
#pragma unroll
  for (int mi = 0; mi < 4; mi++) {
#pragma unroll
    for (int ni = 0; ni < 4; ni++) {
      const int col = n0 + wn * 64 + ni * 16 + l15;
      const int seg = col >> 10;        // 0=k 1=v 2=q (uniform per block)
      const int wcol = col & 1023;
      const int nbq = wcol >> 3, jq = wcol & 7;
#pragma unroll
      for (int r = 0; r < 4; r++) {
        const int rowg = m0 + wm * 64 + mi * 16 + quad * 4 + r;
        const int t = rowg >> 3, bq = rowg & 7;
        float val = acc[mi][ni][r];
        const size_t cb = (size_t)(bq * NB + nbq) * C_PLANE +
                          (size_t)(t >> 3) * 192;
        size_t addr;
        if (seg == 0) {  // wave-uniform branch
          float ss = reduce8(val * val);  // ||k||^2 over the 8 j-lanes
          float rs = __builtin_amdgcn_rcpf(__builtin_amdgcn_sqrtf(ss) + 1e-6f);
          val *= rs;
          addr = cb + (jq >> 2) * 32 + (t & 7) * 4 + (jq & 3);
        } else if (seg == 1) {
          addr = cb + 64 + jq * 8 + (t & 7);        // jq == row index i
        } else {
          addr = cb + 128 + (jq >> 2) * 32 + (t & 7) * 4 + (jq & 3);
        }
        pk[addr] = f2bf(val);
      }
    }
  }
}

// ---------------- Kernel 3: scan, 4 elems/lane, 4 chains/wave --------------
// 256 blocks x 64 threads (1 wave). lane = c*16 + i*2 + h:
//   c = chain-within-wave (4 chains), i = state row, h = column half.
// Lane holds S[i][4h..4h+3] in 4 registers. Row-dot = in-lane fma tree +
// ONE dpp_add (lane^1) -- replaces the 3-stage DPP butterfly of the old
// element-per-lane layout (16 -> 10.5 dependency levels/step) and cuts
// per-chain issue ~4x (no redundant all-lane reduces).
// SS = S * 2log2e maintained in parallel with S (same rcp producer) so the
// exp2 argument needs no extra multiply on the critical path.
#define C_2LOG2E 2.8853900817779268f   // 2*log2(e)
#define C_LOG2E  1.4426950408889634f

__global__ __launch_bounds__(64) void scan_kernel(
    const unsigned short* __restrict__ pk, float* __restrict__ out) {
  const int blk = blockIdx.x;          // 0..255
  const int lane = threadIdx.x;
  const int c = lane >> 4, i = (lane >> 1) & 7, h = lane & 1;
  const int chain = blk * 4 + c;
  const int b = chain >> 7, nb = chain & 127;

  const unsigned short* pc = pk + (size_t)chain * C_PLANE;
  const int koff = h * 32;         // ushort offset of this lane's k chunk
  const int voff = 64 + i * 8;
  const int qoff = 128 + h * 32;

  float S0 = 0.f, S1 = 0.f, S2 = 0.f, S3 = 0.f;      // raw state
  float T0 = 0.f, T1 = 0.f, T2 = 0.f, T3 = 0.f;      // S * 2log2e

  // current-buffer registers
  uintx4 ck0, ck1, ck2, ck3, cq0, cq1, cq2, cq3, cv;
  {
    const unsigned short* rec = pc;
    const uintx4* kp = (const uintx4*)(rec + koff);
    const uintx4* qp = (const uintx4*)(rec + qoff);
    ck0 = kp[0]; ck1 = kp[1]; ck2 = kp[2]; ck3 = kp[3];
    cq0 = qp[0]; cq1 = qp[1]; cq2 = qp[2]; cq3 = qp[3];
    cv = *(const uintx4*)(rec + voff);
  }

  float* outp = out + (size_t)b * NSTATE + nb * BLKSZ + i;
  const bool writer = (h == 0);

  for (int tb = 0; tb < 256; tb++) {
    const int nxt = (tb < 255) ? tb + 1 : 255;       // clamp: harmless re-read
    const unsigned short* rec = pc + (size_t)nxt * 192;
    const uintx4* kp = (const uintx4*)(rec + koff);
    const uintx4* qp = (const uintx4*)(rec + qoff);
    uintx4 nk0 = kp[0], nk1 = kp[1], nk2 = kp[2], nk3 = kp[3];
    uintx4 nq0 = qp[0], nq1 = qp[1], nq2 = qp[2], nq3 = qp[3];
    uintx4 nv = *(const uintx4*)(rec + voff);

#pragma unroll
    for (int u = 0; u < 8; u++) {
      // pick this step's packed words (all indices compile-time)
      unsigned kwA, kwB, qwA, qwB;
      switch (u >> 1) {
        case 0: kwA = ck0[(u & 1) * 2]; kwB = ck0[(u & 1) * 2 + 1];
                qwA = cq0[(u & 1) * 2]; qwB = cq0[(u & 1) * 2 + 1]; break;
        case 1: kwA = ck1[(u & 1) * 2]; kwB = ck1[(u & 1) * 2 + 1];
                qwA = cq1[(u & 1) * 2]; qwB = cq1[(u & 1) * 2 + 1]; break;
        case 2: kwA = ck2[(u & 1) * 2]; kwB = ck2[(u & 1) * 2 + 1];
                qwA = cq2[(u & 1) * 2]; qwB = cq2[(u & 1) * 2 + 1]; break;
        default: kwA = ck3[(u & 1) * 2]; kwB = ck3[(u & 1) * 2 + 1];
                 qwA = cq3[(u & 1) * 2]; qwB = cq3[(u & 1) * 2 + 1]; break;
      }
      float k0 = bfu(kwA, 0), k1 = bfu(kwA, 1);
      float k2 = bfu(kwB, 0), k3 = bfu(kwB, 1);
      float q0 = bfu(qwA, 0), q1 = bfu(qwA, 1);
      float q2 = bfu(qwB, 0), q3 = bfu(qwB, 1);
      float vf = bfu(cv[u >> 1], u & 1);
      float vC = vf * C_2LOG2E;            // off critical path

      // retrieved_i = sum_j S[i][j]*kn[j]: in-lane tree + 1 dpp
      float p01 = fmaf(S1, k1, S0 * k0);
      float p23 = fmaf(S3, k3, S2 * k2);
      float rp = p01 + p23;
      float r = dpp_add<0xB1>(rp);         // + partner half (lane^1)

      // dC = (v - r) * 2log2e, fused
      float dC = fmaf(-C_2LOG2E, r, vC);

      // S = tanh(S + delta*kn), arg pre-scaled via shadow state T
      float a0 = fmaf(dC, k0, T0), a1 = fmaf(dC, k1, T1);
      float a2 = fmaf(dC, k2, T2), a3 = fmaf(dC, k3, T3);
      float e0 = __builtin_amdgcn_exp2f(a0);
      float e1 = __builtin_amdgcn_exp2f(a1);
      float e2 = __builtin_amdgcn_exp2f(a2);
      float e3 = __builtin_amdgcn_exp2f(a3);
      float r0 = __builtin_amdgcn_rcpf(e0 + 1.f);
      float r1 = __builtin_amdgcn_rcpf(e1 + 1.f);
      float r2 = __builtin_amdgcn_rcpf(e2 + 1.f);
      float r3 = __builtin_amdgcn_rcpf(e3 + 1.f);
      S0 = fmaf(-2.f, r0, 1.f); T0 = fmaf(-2.f * C_2LOG2E, r0, C_2LOG2E);
      S1 = fmaf(-2.f, r1, 1.f); T1 = fmaf(-2.f * C_2LOG2E, r1, C_2LOG2E);
      S2 = fmaf(-2.f, r2, 1.f); T2 = fmaf(-2.f * C_2LOG2E, r2, C_2LOG2E);
      S3 = fmaf(-2.f, r3, 1.f); T3 = fmaf(-2.f * C_2LOG2E, r3, C_2LOG2E);

      // z_i = sum_j S[i][j]*q[j]; out = z^2 * sigmoid(z)
      float z01 = fmaf(S1, q1, S0 * q0);
      float z23 = fmaf(S3, q3, S2 * q2);
      float zp = z01 + z23;
      float z = dpp_add<0xB1>(zp);
      float sig =
          __builtin_amdgcn_rcpf(1.f + __builtin_amdgcn_exp2f(-z * C_LOG2E));
      float o = z * z * sig;
      if (writer) outp[(size_t)(tb * 8 + u) * (B_DIM * NSTATE)] = o;
    }
    ck0 = nk0; ck1 = nk1; ck2 = nk2; ck3 = nk3;
    cq0 = nq0; cq1 = nq1; cq2 = nq2; cq3 = nq3;
    cv = nv;
  }

  // S_final: [B][NB][8][8]; lane (c,i,h) -> elements i*8+4h.. , float4 store
  const size_t fin = (size_t)T_DIM * B_DIM * NSTATE;
  float4 sf = {S0, S1, S2, S3};
  *(float4*)(out + fin + (size_t)chain * 64 + i * 8 + h * 4) = sf;
}

// ---------------- launch ---------------------------------------------------
extern "C" void kernel_launch(void* const* d_in, const int* in_sizes, int n_in,
                              void* d_out, int out_size, void* d_ws,
                              size_t ws_size, hipStream_t stream) {
  const float* x = (const float*)d_in[0];
  const float* Wk = (const float*)d_in[1];
  const float* Wv = (const float*)d_in[2];
  const float* Wq = (const float*)d_in[3];
  float* out = (float*)d_out;

  unsigned short* xb = (unsigned short*)d_ws;                  // 32 MiB
  unsigned short* wb = xb + (size_t)M_DIM * K_DIM;             // 6 MiB
  unsigned short* pk = wb + (size_t)N_DIM * K_DIM;             // 96 MiB packed

  convert_kernel<<<M_DIM + N_DIM, 256, 0, stream>>>(x, Wk, Wv, Wq, xb, wb);
  gemm_kernel<<<(M_DIM / BM) * (N_DIM / BN), 256, 0, stream>>>(xb, wb, pk);
  scan_kernel<<<B_DIM * NB / 4, 64, 0, stream>>>(pk, out);
}

// Round 4
// 559.741 us; speedup vs baseline: 1.1688x; 1.0801x over previous
//
#include <hip/hip_runtime.h>
#include <hip/hip_bf16.h>
#include <stdint.h>

// Problem constants
#define T_DIM 2048
#define B_DIM 8
#define D_DIM 1024
#define NSTATE 1024
#define BLKSZ 8
#define NB 128
#define M_DIM (T_DIM * B_DIM)   // 16384
#define N_DIM (3 * NSTATE)      // 3072 (k | v | q concatenated)
#define K_DIM D_DIM             // 1024

typedef __bf16 bf16x8 __attribute__((ext_vector_type(8)));
typedef float f32x4 __attribute__((ext_vector_type(4)));
typedef unsigned int uintx4 __attribute__((ext_vector_type(4)));

typedef __attribute__((address_space(3))) void lds_void;
typedef __attribute__((address_space(1))) const void glb_void;

__device__ __forceinline__ unsigned short f2bf(float f) {
  unsigned u = __float_as_uint(f);
  u = (u + 0x7FFFu + ((u >> 16) & 1u)) >> 16;  // RNE
  return (unsigned short)u;
}
// unpack bf16 #hi (0=low,1=high) from a packed u32, as float (1 VALU op)
__device__ __forceinline__ float bfu(unsigned r, int hi) {
  return __uint_as_float(hi ? (r & 0xFFFF0000u) : (r << 16));
}

__device__ __forceinline__ void load_lds16(const unsigned short* g,
                                           unsigned short* l) {
  __builtin_amdgcn_global_load_lds((glb_void*)g, (lds_void*)l, 16, 0, 0);
}

// DPP butterfly add (groups = physical lanes 8k..8k+7)
template <int CTRL>
__device__ __forceinline__ float dpp_add(float x) {
  int y = __builtin_amdgcn_update_dpp(0, __float_as_int(x), CTRL, 0xF, 0xF, true);
  return x + __int_as_float(y);
}
__device__ __forceinline__ float reduce8(float x) {
  x = dpp_add<0xB1>(x);   // quad_perm(1,0,3,2): lane ^ 1
  x = dpp_add<0x4E>(x);   // quad_perm(2,3,0,1): lane ^ 2
  x = dpp_add<0x141>(x);  // row_half_mirror: crosses quads within 8-group
  return x;
}

// ---------------- Kernel 1: fp32 -> bf16 conversion of x and Wcat ----------
__global__ __launch_bounds__(256) void convert_kernel(
    const float* __restrict__ x, const float* __restrict__ Wk,
    const float* __restrict__ Wv, const float* __restrict__ Wq,
    unsigned short* __restrict__ xb, unsigned short* __restrict__ wb) {
  size_t idx = (size_t)blockIdx.x * blockDim.x + threadIdx.x;
  size_t row = idx >> 8;
  int c4 = (int)(idx & 255) * 4;
  const float* src;
  unsigned short* dst;
  if (row < (size_t)M_DIM) {
    src = x + row * K_DIM;
    dst = xb + row * K_DIM;
  } else {
    size_t r = row - M_DIM;
    const float* w = (r < 1024) ? Wk : (r < 2048 ? Wv : Wq);
    src = w + (r & 1023) * K_DIM;
    dst = wb + r * K_DIM;
  }
  float4 v = *(const float4*)(src + c4);
  ushort4 o;
  o.x = f2bf(v.x); o.y = f2bf(v.y); o.z = f2bf(v.z); o.w = f2bf(v.w);
  *(ushort4*)(dst + c4) = o;
}

// ---------------- Kernel 2: bf16 MFMA GEMM, chain-major packed epilogue ----
// pk layout per chain, per 8-step block (tblk = t/8), 192 ushorts:
//   seg*64 + elem*8 + (t%8)   with seg 0=k 1=v 2=q, elem = j (k,q) or i (v).
// Scan lane (i,j) then streams k[j]/v[i]/q[j] for 8 steps as one dwordx4
// each. k is normalized IN the epilogue (fp32, DPP reduce over 8 j-lanes).
#define BM 128
#define BN 128
#define BK 32
#define C_PLANE 49152  // ushorts per chain (256 tblk * 192)

__global__ __launch_bounds__(256) void gemm_kernel(
    const unsigned short* __restrict__ A,     // [M][K] bf16
    const unsigned short* __restrict__ Bmat,  // [N][K] bf16
    unsigned short* __restrict__ pk) {        // packed, layout above
  __shared__ unsigned short As[BM * BK];  // swizzled, unpadded
  __shared__ unsigned short Bs[BN * BK];

  const int tid = threadIdx.x;
  const int nTiles = N_DIM / BN;  // 24
  const int nTile = blockIdx.x % nTiles;
  const int mTile = blockIdx.x / nTiles;
  const int m0 = mTile * BM, n0 = nTile * BN;

  const int lane = tid & 63, wave = tid >> 6;
  const int wm = wave >> 1, wn = wave & 1;
  const int l15 = lane & 15, quad = lane >> 4;
  const int sw = quad ^ ((l15 >> 1) & 3);

  const int srow = lane >> 2;
  const int sblk = (lane & 3) ^ ((lane >> 3) & 3);
  const int c0 = wave, c1 = wave + 4;

  const unsigned short* gA0 = A + (size_t)(m0 + c0 * 16 + srow) * K_DIM + sblk * 8;
  const unsigned short* gA1 = A + (size_t)(m0 + c1 * 16 + srow) * K_DIM + sblk * 8;
  const unsigned short* gB0 = Bmat + (size_t)(n0 + c0 * 16 + srow) * K_DIM + sblk * 8;
  const unsigned short* gB1 = Bmat + (size_t)(n0 + c1 * 16 + srow) * K_DIM + sblk * 8;

  f32x4 acc[4][4];
#pragma unroll
  for (int mi = 0; mi < 4; mi++)
#pragma unroll
    for (int ni = 0; ni < 4; ni++) acc[mi][ni] = (f32x4){0.f, 0.f, 0.f, 0.f};

  for (int k0 = 0; k0 < K_DIM; k0 += BK) {
    __syncthreads();
    load_lds16(gA0 + k0, As + c0 * 512);
    load_lds16(gA1 + k0, As + c1 * 512);
    load_lds16(gB0 + k0, Bs + c0 * 512);
    load_lds16(gB1 + k0, Bs + c1 * 512);
    __syncthreads();

    bf16x8 af[4], bfr[4];
#pragma unroll
    for (int mi = 0; mi < 4; mi++) {
      uintx4 r = *(const uintx4*)(As + (wm * 64 + mi * 16 + l15) * BK + sw * 8);
      af[mi] = __builtin_bit_cast(bf16x8, r);
    }
#pragma unroll
    for (int ni = 0; ni < 4; ni++) {
      uintx4 r = *(const uintx4*)(Bs + (wn * 64 + ni * 16 + l15) * BK + sw * 8);
      bfr[ni] = __builtin_bit_cast(bf16x8, r);
    }
#pragma unroll
    for (int mi = 0; mi < 4; mi++)
#pragma unroll
      for (int ni = 0; ni < 4; ni++)
        acc[mi][ni] = __builtin_amdgcn_mfma_f32_16x16x32_bf16(
            af[mi], bfr[ni], acc[mi][ni], 0, 0, 0);
  }

  // Epilogue: scatter into chain-major records; normalize k-segment rows.
#pragma unroll
  for (int mi = 0; mi < 4; mi++) {
#pragma unroll
    for (int ni = 0; ni < 4; ni++) {
      const int col = n0 + wn * 64 + ni * 16 + l15;
      const int seg = col >> 10;        // 0=k 1=v 2=q (uniform per block)
      const int wcol = col & 1023;
      const int nbq = wcol >> 3, jq = wcol & 7;
#pragma unroll
      for (int r = 0; r < 4; r++) {
        const int rowg = m0 + wm * 64 + mi * 16 + quad * 4 + r;
        const int t = rowg >> 3, bq = rowg & 7;
        float val = acc[mi][ni][r];
        if (seg == 0) {  // wave-uniform branch
          float ss = reduce8(val * val);  // ||k||^2 over the 8 j-lanes
          float rs = __builtin_amdgcn_rcpf(__builtin_amdgcn_sqrtf(ss) + 1e-6f);
          val *= rs;
        }
        const size_t addr = (size_t)(bq * NB + nbq) * C_PLANE +
                            (size_t)(t >> 3) * 192 + seg * 64 + jq * 8 +
                            (t & 7);
        pk[addr] = f2bf(val);
      }
    }
  }
}

// ---------------- Kernel 3: scan, element-per-lane, 3-buffer pipeline ------
// One chain per 64-lane wave, 1024 blocks (4/CU -> all 4 SIMDs busy).
// __launch_bounds__(64,1): min 1 wave/EU -> full 512-VGPR budget, so the
// triple-buffered prefetch (9 dwordx4 live) actually stays in registers.
// Each buffer is reloaded right after consumption -> its next use is 16
// steps (~2000 cy) away: covers HBM-miss latency, no vmcnt(0) on the
// consume path. (Rounds 0-2 were silently register-capped at 28-52 VGPRs,
// which collapsed the prefetch distance -> ~100-220 cy/step load stalls.)
#define C_2LOG2E 2.8853900817779268f   // 2*log2(e)
#define C_LOG2E  1.4426950408889634f

__device__ __forceinline__ void step1(float& S, float& T, float kf, float vf,
                                      float qf, float& o) {
  // retrieved_i = sum_j S[i][j]*kn[j]  (k pre-normalized)
  float p = S * kf;
  p = dpp_add<0xB1>(p);
  p = dpp_add<0x4E>(p);
  p = dpp_add<0x141>(p);
  // dC = (v - retrieved) * 2log2e, fused; T = S*2log2e shadow state
  float dC = fmaf(-C_2LOG2E, p, vf * C_2LOG2E);
  float a = fmaf(dC, kf, T);
  float e = __builtin_amdgcn_exp2f(a);
  float r = __builtin_amdgcn_rcpf(e + 1.f);
  S = fmaf(-2.f, r, 1.f);
  T = fmaf(-2.f * C_2LOG2E, r, C_2LOG2E);
  // z_i = sum_j S[i][j]*q[j]; out = z^2 * sigmoid(z)
  float z = S * qf;
  z = dpp_add<0xB1>(z);
  z = dpp_add<0x4E>(z);
  z = dpp_add<0x141>(z);
  float sig = __builtin_amdgcn_rcpf(1.f + __builtin_amdgcn_exp2f(-z * C_LOG2E));
  o = z * z * sig;
}

__global__ __launch_bounds__(64, 1) void scan_kernel(
    const unsigned short* __restrict__ pk, float* __restrict__ out) {
  const int chain = blockIdx.x;        // b*128+nb
  const int b = chain >> 7, nb = chain & 127;
  const int lane = threadIdx.x;
  const int i = lane >> 3, j = lane & 7;

  const unsigned short* pc = pk + (size_t)chain * C_PLANE;
  const int koff = j * 8, voff = 64 + i * 8, qoff = 128 + j * 8;

  float S = 0.f, T = 0.f;
  float* outp = out + (size_t)b * NSTATE + nb * BLKSZ + i;
  const bool writer = (j == 0);

#define RELOAD(RK, RV, RQ, TNEXT)                          \
  {                                                        \
    const unsigned short* rec = pc + (size_t)(TNEXT) * 192;\
    RK = *(const uintx4*)(rec + koff);                     \
    RV = *(const uintx4*)(rec + voff);                     \
    RQ = *(const uintx4*)(rec + qoff);                     \
  }

#define CONSUME(RK, RV, RQ, TBASE)                                         \
  _Pragma("unroll") for (int u = 0; u < 8; u++) {                          \
    float kf = bfu(RK[u >> 1], u & 1);                                     \
    float vf = bfu(RV[u >> 1], u & 1);                                     \
    float qf = bfu(RQ[u >> 1], u & 1);                                     \
    float o;                                                               \
    step1(S, T, kf, vf, qf, o);                                            \
    if (writer)                                                            \
      outp[(size_t)((TBASE) * 8 + u) * (B_DIM * NSTATE)] = o;              \
  }

  uintx4 bk0, bv0, bq0, bk1, bv1, bq1, bk2, bv2, bq2;
  RELOAD(bk0, bv0, bq0, 0);
  RELOAD(bk1, bv1, bq1, 1);
  RELOAD(bk2, bv2, bq2, 2);

  // 255 = 85*3 tblks in the pipelined loop; tblk 255 is the drain tail.
  for (int tb = 0; tb < 255; tb += 3) {
    CONSUME(bk0, bv0, bq0, tb);
    RELOAD(bk0, bv0, bq0, (tb + 3 < 256) ? tb + 3 : 255);
    CONSUME(bk1, bv1, bq1, tb + 1);
    RELOAD(bk1, bv1, bq1, (tb + 4 < 256) ? tb + 4 : 255);
    CONSUME(bk2, bv2, bq2, tb + 2);
    RELOAD(bk2, bv2, bq2, (tb + 5 < 256) ? tb + 5 : 255);
  }
  CONSUME(bk0, bv0, bq0, 255);

#undef RELOAD
#undef CONSUME

  // S_final: [B][NB][8][8]; lane (i,j) -> element i*8+j, coalesced
  out[(size_t)T_DIM * B_DIM * NSTATE + (size_t)chain * 64 + lane] = S;
}

// ---------------- launch ---------------------------------------------------
extern "C" void kernel_launch(void* const* d_in, const int* in_sizes, int n_in,
                              void* d_out, int out_size, void* d_ws,
                              size_t ws_size, hipStream_t stream) {
  const float* x = (const float*)d_in[0];
  const float* Wk = (const float*)d_in[1];
  const float* Wv = (const float*)d_in[2];
  const float* Wq = (const float*)d_in[3];
  float* out = (float*)d_out;

  unsigned short* xb = (unsigned short*)d_ws;                  // 32 MiB
  unsigned short* wb = xb + (size_t)M_DIM * K_DIM;             // 6 MiB
  unsigned short* pk = wb + (size_t)N_DIM * K_DIM;             // 96 MiB packed

  convert_kernel<<<M_DIM + N_DIM, 256, 0, stream>>>(x, Wk, Wv, Wq, xb, wb);
  gemm_kernel<<<(M_DIM / BM) * (N_DIM / BN), 256, 0, stream>>>(xb, wb, pk);
  scan_kernel<<<B_DIM * NB, 64, 0, stream>>>(pk, out);
}

// Round 5
// 489.217 us; speedup vs baseline: 1.3373x; 1.1442x over previous
//
#include <hip/hip_runtime.h>
#include <hip/hip_bf16.h>
#include <stdint.h>

// Problem constants
#define T_DIM 2048
#define B_DIM 8
#define D_DIM 1024
#define NSTATE 1024
#define BLKSZ 8
#define NB 128
#define M_DIM (T_DIM * B_DIM)   // 16384
#define N_DIM (3 * NSTATE)      // 3072 (k | v | q concatenated)
#define K_DIM D_DIM             // 1024

typedef __bf16 bf16x8 __attribute__((ext_vector_type(8)));
typedef float f32x4 __attribute__((ext_vector_type(4)));
typedef unsigned int uintx4 __attribute__((ext_vector_type(4)));

typedef __attribute__((address_space(3))) void lds_void;
typedef __attribute__((address_space(1))) const void glb_void;

__device__ __forceinline__ unsigned short f2bf(float f) {
  unsigned u = __float_as_uint(f);
  u = (u + 0x7FFFu + ((u >> 16) & 1u)) >> 16;  // RNE
  return (unsigned short)u;
}
// unpack bf16 #hi (0=low,1=high) from a packed u32, as float (1 VALU op)
__device__ __forceinline__ float bfu(unsigned r, int hi) {
  return __uint_as_float(hi ? (r & 0xFFFF0000u) : (r << 16));
}

__device__ __forceinline__ void load_lds16(const unsigned short* g,
                                           unsigned short* l) {
  __builtin_amdgcn_global_load_lds((glb_void*)g, (lds_void*)l, 16, 0, 0);
}

// DPP butterfly add (groups = physical lanes 8k..8k+7); compiler folds the
// update_dpp(0,...) + add into a single v_add_f32 dpp instruction.
template <int CTRL>
__device__ __forceinline__ float dpp_add(float x) {
  int y = __builtin_amdgcn_update_dpp(0, __float_as_int(x), CTRL, 0xF, 0xF, true);
  return x + __int_as_float(y);
}
// bare DPP move (value from the mirrored lane)
template <int CTRL>
__device__ __forceinline__ float dpp_mov(float x) {
  int y = __builtin_amdgcn_update_dpp(0, __float_as_int(x), CTRL, 0xF, 0xF, true);
  return __int_as_float(y);
}
__device__ __forceinline__ float reduce8(float x) {
  x = dpp_add<0xB1>(x);   // quad_perm(1,0,3,2): lane ^ 1
  x = dpp_add<0x4E>(x);   // quad_perm(2,3,0,1): lane ^ 2
  x = dpp_add<0x141>(x);  // row_half_mirror: crosses quads within 8-group
  return x;
}

// ---------------- Kernel 1: fp32 -> bf16 conversion of x and Wcat ----------
__global__ __launch_bounds__(256) void convert_kernel(
    const float* __restrict__ x, const float* __restrict__ Wk,
    const float* __restrict__ Wv, const float* __restrict__ Wq,
    unsigned short* __restrict__ xb, unsigned short* __restrict__ wb) {
  size_t idx = (size_t)blockIdx.x * blockDim.x + threadIdx.x;
  size_t row = idx >> 8;
  int c4 = (int)(idx & 255) * 4;
  const float* src;
  unsigned short* dst;
  if (row < (size_t)M_DIM) {
    src = x + row * K_DIM;
    dst = xb + row * K_DIM;
  } else {
    size_t r = row - M_DIM;
    const float* w = (r < 1024) ? Wk : (r < 2048 ? Wv : Wq);
    src = w + (r & 1023) * K_DIM;
    dst = wb + r * K_DIM;
  }
  float4 v = *(const float4*)(src + c4);
  ushort4 o;
  o.x = f2bf(v.x); o.y = f2bf(v.y); o.z = f2bf(v.z); o.w = f2bf(v.w);
  *(ushort4*)(dst + c4) = o;
}

// ---------------- Kernel 2: bf16 MFMA GEMM, chain-major packed epilogue ----
// pk layout per chain, per 8-step block (tblk = t/8), 192 ushorts:
//   seg*64 + elem*8 + (t%8)   with seg 0=k 1=v 2=q, elem = j (k,q) or i (v).
// Scan lane (i,j) then streams k[j]/v[i]/q[j] for 8 steps as one dwordx4
// each. k is normalized IN the epilogue (fp32, DPP reduce over 8 j-lanes).
#define BM 128
#define BN 128
#define BK 32
#define C_PLANE 49152  // ushorts per chain (256 tblk * 192)

__global__ __launch_bounds__(256) void gemm_kernel(
    const unsigned short* __restrict__ A,     // [M][K] bf16
    const unsigned short* __restrict__ Bmat,  // [N][K] bf16
    unsigned short* __restrict__ pk) {        // packed, layout above
  __shared__ unsigned short As[BM * BK];  // swizzled, unpadded
  __shared__ unsigned short Bs[BN * BK];

  const int tid = threadIdx.x;
  const int nTiles = N_DIM / BN;  // 24
  const int nTile = blockIdx.x % nTiles;
  const int mTile = blockIdx.x / nTiles;
  const int m0 = mTile * BM, n0 = nTile * BN;

  const int lane = tid & 63, wave = tid >> 6;
  const int wm = wave >> 1, wn = wave & 1;
  const int l15 = lane & 15, quad = lane >> 4;
  const int sw = quad ^ ((l15 >> 1) & 3);

  const int srow = lane >> 2;
  const int sblk = (lane & 3) ^ ((lane >> 3) & 3);
  const int c0 = wave, c1 = wave + 4;

  const unsigned short* gA0 = A + (size_t)(m0 + c0 * 16 + srow) * K_DIM + sblk * 8;
  const unsigned short* gA1 = A + (size_t)(m0 + c1 * 16 + srow) * K_DIM + sblk * 8;
  const unsigned short* gB0 = Bmat + (size_t)(n0 + c0 * 16 + srow) * K_DIM + sblk * 8;
  const unsigned short* gB1 = Bmat + (size_t)(n0 + c1 * 16 + srow) * K_DIM + sblk * 8;

  f32x4 acc[4][4];
#pragma unroll
  for (int mi = 0; mi < 4; mi++)
#pragma unroll
    for (int ni = 0; ni < 4; ni++) acc[mi][ni] = (f32x4){0.f, 0.f, 0.f, 0.f};

  for (int k0 = 0; k0 < K_DIM; k0 += BK) {
    __syncthreads();
    load_lds16(gA0 + k0, As + c0 * 512);
    load_lds16(gA1 + k0, As + c1 * 512);
    load_lds16(gB0 + k0, Bs + c0 * 512);
    load_lds16(gB1 + k0, Bs + c1 * 512);
    __syncthreads();

    bf16x8 af[4], bfr[4];
#pragma unroll
    for (int mi = 0; mi < 4; mi++) {
      uintx4 r = *(const uintx4*)(As + (wm * 64 + mi * 16 + l15) * BK + sw * 8);
      af[mi] = __builtin_bit_cast(bf16x8, r);
    }
#pragma unroll
    for (int ni = 0; ni < 4; ni++) {
      uintx4 r = *(const uintx4*)(Bs + (wn * 64 + ni * 16 + l15) * BK + sw * 8);
      bfr[ni] = __builtin_bit_cast(bf16x8, r);
    }
#pragma unroll
    for (int mi = 0; mi < 4; mi++)
#pragma unroll
      for (int ni = 0; ni < 4; ni++)
        acc[mi][ni] = __builtin_amdgcn_mfma_f32_16x16x32_bf16(
            af[mi], bfr[ni], acc[mi][ni], 0, 0, 0);
  }

  // Epilogue: scatter into chain-major records; normalize k-segment rows.
#pragma unroll
  for (int mi = 0; mi < 4; mi++) {
#pragma unroll
    for (int ni = 0; ni < 4; ni++) {
      const int col = n0 + wn * 64 + ni * 16 + l15;
      const int seg = col >> 10;        // 0=k 1=v 2=q (uniform per block)
      const int wcol = col & 1023;
      const int nbq = wcol >> 3, jq = wcol & 7;
#pragma unroll
      for (int r = 0; r < 4; r++) {
        const int rowg = m0 + wm * 64 + mi * 16 + quad * 4 + r;
        const int t = rowg >> 3, bq = rowg & 7;
        float val = acc[mi][ni][r];
        if (seg == 0) {  // wave-uniform branch
          float ss = reduce8(val * val);  // ||k||^2 over the 8 j-lanes
          float rs = __builtin_amdgcn_rcpf(__builtin_amdgcn_sqrtf(ss) + 1e-6f);
          val *= rs;
        }
        const size_t addr = (size_t)(bq * NB + nbq) * C_PLANE +
                            (size_t)(t >> 3) * 192 + seg * 64 + jq * 8 +
                            (t & 7);
        pk[addr] = f2bf(val);
      }
    }
  }
}

// ---------------- Kernel 3: scan, element-per-lane, pinned 3-buf pipeline --
// One chain per 64-lane wave, 1024 blocks (4/CU, 1 wave/SIMD).
// sched_barrier(0) after each {consume|reload} region pins the triple
// buffer: loads may hoist into the preceding consume but cannot sink into
// the next one (R4 showed the compiler sinks them otherwise: VGPR=28).
// z-transpose: per step each lane keeps z only when j==u (cndmask); after 8
// steps the wave holds all 64 (i, t%8) z values one-per-lane -> ONE exp2 +
// ONE rcp + ONE coalesced store per tblk (trans issue 64->36 cy/step).
#define C_2LOG2E 2.8853900817779268f   // 2*log2(e)
#define C_LOG2E  1.4426950408889634f

__global__ __launch_bounds__(64, 1) void scan_kernel(
    const unsigned short* __restrict__ pk, float* __restrict__ out) {
  const int chain = blockIdx.x;        // b*128+nb
  const int b = chain >> 7, nb = chain & 127;
  const int lane = threadIdx.x;
  const int i = lane >> 3, j = lane & 7;

  const unsigned short* pc = pk + (size_t)chain * C_PLANE;
  const int koff = j * 8, voff = 64 + i * 8, qoff = 128 + j * 8;

  float S = 0.f, T = 0.f, zsel = 0.f;
  // per-lane output pointer: t = tb*8 + j, column b*1024+nb*8+i
  float* outp = out + (size_t)j * (B_DIM * NSTATE) + b * NSTATE + nb * BLKSZ + i;

#define RELOAD(RK, RV, RQ, TNEXT)                          \
  {                                                        \
    const unsigned short* rec = pc + (size_t)(TNEXT) * 192;\
    RK = *(const uintx4*)(rec + koff);                     \
    RV = *(const uintx4*)(rec + voff);                     \
    RQ = *(const uintx4*)(rec + qoff);                     \
  }

#define CONSUME(RK, RV, RQ)                                                 \
  {                                                                         \
    _Pragma("unroll") for (int u = 0; u < 8; u++) {                         \
      float kf = bfu(RK[u >> 1], u & 1);                                    \
      float vf = bfu(RV[u >> 1], u & 1);                                    \
      float qf = bfu(RQ[u >> 1], u & 1);                                    \
      float kC = kf * C_2LOG2E;            /* off critical path */          \
      float base = fmaf(kC, vf, T);        /* off critical path */          \
      float p = S * kf;                                                     \
      p = dpp_add<0xB1>(p);                /* + lane^1 */                   \
      p = dpp_add<0x4E>(p);                /* + lane^2 -> quad sum q4 */    \
      float q4m = dpp_mov<0x141>(p);       /* partner quad's q4 */          \
      float u1 = fmaf(-kC, p, base);       /* parallel with dpp_mov */      \
      float a = fmaf(-kC, q4m, u1);        /* = T + kC*(v - sum8) */        \
      float e = __builtin_amdgcn_exp2f(a);                                  \
      float r_ = __builtin_amdgcn_rcpf(e + 1.f);                            \
      S = fmaf(-2.f, r_, 1.f);                                              \
      T = fmaf(-2.f * C_2LOG2E, r_, C_2LOG2E);                              \
      float z = S * qf;                                                     \
      z = dpp_add<0xB1>(z);                                                 \
      z = dpp_add<0x4E>(z);                                                 \
      z = dpp_add<0x141>(z);                                                \
      zsel = (j == u) ? z : zsel;          /* keeper lane for step u */     \
    }                                                                       \
    /* per-tblk epilogue: one trans pair + one full-wave coalesced store */ \
    float sg = __builtin_amdgcn_rcpf(                                       \
        1.f + __builtin_amdgcn_exp2f(zsel * -C_LOG2E));                     \
    *outp = zsel * zsel * sg;                                               \
    outp += 8 * (B_DIM * NSTATE);                                           \
  }

  uintx4 bk0, bv0, bq0, bk1, bv1, bq1, bk2, bv2, bq2;
  RELOAD(bk0, bv0, bq0, 0);
  RELOAD(bk1, bv1, bq1, 1);
  RELOAD(bk2, bv2, bq2, 2);
  __builtin_amdgcn_sched_barrier(0);

  // 255 = 85*3 tblks in the pipelined loop; tblk 255 is the drain tail.
  for (int tb = 0; tb < 255; tb += 3) {
    CONSUME(bk0, bv0, bq0);
    RELOAD(bk0, bv0, bq0, tb + 3);
    __builtin_amdgcn_sched_barrier(0);
    CONSUME(bk1, bv1, bq1);
    RELOAD(bk1, bv1, bq1, (tb + 4 < 256) ? tb + 4 : 255);
    __builtin_amdgcn_sched_barrier(0);
    CONSUME(bk2, bv2, bq2);
    RELOAD(bk2, bv2, bq2, (tb + 5 < 256) ? tb + 5 : 255);
    __builtin_amdgcn_sched_barrier(0);
  }
  CONSUME(bk0, bv0, bq0);

#undef RELOAD
#undef CONSUME

  // S_final: [B][NB][8][8]; lane (i,j) -> element i*8+j, coalesced
  out[(size_t)T_DIM * B_DIM * NSTATE + (size_t)chain * 64 + lane] = S;
}

// ---------------- launch ---------------------------------------------------
extern "C" void kernel_launch(void* const* d_in, const int* in_sizes, int n_in,
                              void* d_out, int out_size, void* d_ws,
                              size_t ws_size, hipStream_t stream) {
  const float* x = (const float*)d_in[0];
  const float* Wk = (const float*)d_in[1];
  const float* Wv = (const float*)d_in[2];
  const float* Wq = (const float*)d_in[3];
  float* out = (float*)d_out;

  unsigned short* xb = (unsigned short*)d_ws;                  // 32 MiB
  unsigned short* wb = xb + (size_t)M_DIM * K_DIM;             // 6 MiB
  unsigned short* pk = wb + (size_t)N_DIM * K_DIM;             // 96 MiB packed

  convert_kernel<<<M_DIM + N_DIM, 256, 0, stream>>>(x, Wk, Wv, Wq, xb, wb);
  gemm_kernel<<<(M_DIM / BM) * (N_DIM / BN), 256, 0, stream>>>(xb, wb, pk);
  scan_kernel<<<B_DIM * NB, 64, 0, stream>>>(pk, out);
}